// Round 7
// baseline (66.475 us; speedup 1.0000x reference)
//
#include <hip/hip_runtime.h>
#include <stdint.h>

constexpr int Bn = 8, Cn = 64, Hn = 128, Wn = 128;
constexpr int HsC = 64, WsC = 64;
constexpr int Kn = 256;                 // C * r^2
constexpr int PX = HsC * WsC;           // 4096 pixels per (t,b) plane
constexpr float DECAYF = 0.25f;

typedef __attribute__((ext_vector_type(8))) short short8v;
typedef __attribute__((ext_vector_type(4))) float f32x4;

#define WAITV(N) asm volatile("s_waitcnt vmcnt(" #N ")" ::: "memory")
#define WAITL0() asm volatile("s_waitcnt lgkmcnt(0)" ::: "memory")
#define BAR() __builtin_amdgcn_s_barrier()

static __device__ __forceinline__ ushort f2bf_rn(float f) {
    uint32_t u = __float_as_uint(f);
    uint32_t r = (u + 0x7FFFu + ((u >> 16) & 1u)) >> 16;
    return (ushort)r;
}
static __device__ __forceinline__ float bf2f(ushort u) {
    return __uint_as_float(((uint32_t)u) << 16);
}

// u8 spikes (0..4) -> 8 bf16 via v_perm byte-LUT (exact). Verified.
static __device__ __forceinline__ short8v unpack8(uint32_t s0, uint32_t s1) {
    uint32_t lo0 = __builtin_amdgcn_perm(0x00000080u, 0x40008000u, s0);
    uint32_t hi0 = __builtin_amdgcn_perm(0x00000040u, 0x40403F00u, s0);
    uint32_t lo1 = __builtin_amdgcn_perm(0x00000080u, 0x40008000u, s1);
    uint32_t hi1 = __builtin_amdgcn_perm(0x00000040u, 0x40403F00u, s1);
    union { uint32_t u[4]; short8v s; } r;
    r.u[0] = __builtin_amdgcn_perm(hi0, lo0, 0x05010400u);
    r.u[1] = __builtin_amdgcn_perm(hi0, lo0, 0x07030602u);
    r.u[2] = __builtin_amdgcn_perm(hi1, lo1, 0x05010400u);
    r.u[3] = __builtin_amdgcn_perm(hi1, lo1, 0x07030602u);
    return r.s;
}

// async 16B global -> LDS (no dest VGPRs; queue depth = vmcnt)
static __device__ __forceinline__ void gload_lds16(const void* gsrc, void* ldst) {
    __builtin_amdgcn_global_load_lds((const __attribute__((address_space(1))) uint32_t*)gsrc,
                                     (__attribute__((address_space(3))) uint32_t*)ldst, 16, 0, 0);
}

// ---------------------------------------------------------------------------
// Kernel 0: weight prep — fold /4, split bf16 hi+lo, PERMUTED for the conv's
// register preload: dst[((wc*8+ks)*64 + lane)*8 + j] =
//   wq(row = wc*16 + (lane&15), k = ks*32 + (lane>>4)*8 + j)
// ---------------------------------------------------------------------------
__global__ __launch_bounds__(256) void wprep_kernel(const float* __restrict__ w,
                                                    ushort* __restrict__ wh,
                                                    ushort* __restrict__ wl) {
    int gid = blockIdx.x * 256 + threadIdx.x;   // 2048 total
    int lane = gid & 63, ks = (gid >> 6) & 7, wc = gid >> 9;
    int row = wc * 16 + (lane & 15);
    int kb = ks * 32 + (lane >> 4) * 8;
    #pragma unroll
    for (int j = 0; j < 8; ++j) {
        float wq = w[row * 256 + kb + j] * 0.25f;
        ushort h = f2bf_rn(wq);
        wh[gid * 8 + j] = h;
        wl[gid * 8 + j] = f2bf_rn(wq - bf2f(h));
    }
}

// ---------------------------------------------------------------------------
// stage one t's x tile (64c x 2rows x 64cols = 32KB) into LDS buffer.
// ---------------------------------------------------------------------------
static __device__ __forceinline__ void stage_tile(const float* __restrict__ x,
                                                  uint8_t* xb, int t, int b,
                                                  int hs, int half, int wid, int lane) {
    const size_t tstr = (size_t)Bn * Cn * Hn * Wn;
    #pragma unroll
    for (int i = 0; i < 4; ++i) {
        int grp = i * 8 + wid;
        int q = 4 * grp + (lane >> 4);
        int cch = q >> 1, row = q & 1;
        const float* gsrc = x + (size_t)t * tstr + ((size_t)b * Cn + cch) * (Hn * Wn)
                            + (2 * hs + row) * Wn + half * 64 + (lane & 15) * 4;
        gload_lds16(gsrc, xb + (size_t)grp * 1024);
    }
}

// ---------------------------------------------------------------------------
// Fused LIF + 1x1 conv (low res; conv commutes with bilinear upsample).
// Raw s_barrier + counted vmcnt (never 0 mid-loop). Weights in registers.
// UNCHANGED from round 6 (verified vmcnt ledger).
// ---------------------------------------------------------------------------
__global__ __launch_bounds__(512, 4) void fused_lif_conv(const float* __restrict__ x,
                                                         const ushort* __restrict__ wh,
                                                         const ushort* __restrict__ wl,
                                                         ushort* __restrict__ y) {
    __shared__ __align__(16) uint8_t xbuf[2][32 * 1024];  // 64 KB x double-buffer
    __shared__ __align__(16) uint8_t sp_lds[32 * 256];    // 8 KB spikes [px][k]
    __shared__ __align__(8)  uint8_t y_lds[32 * 128];     // 4 KB [px][c] bf16

    const int tid  = threadIdx.x;
    const int pxl  = tid & 31;          // local pixel
    const int cg   = tid >> 5;          // 0..15 -> channels cg*4..cg*4+3
    const int lane = tid & 63;
    const int wid  = tid >> 6;          // 0..7
    const int l15  = lane & 15;
    const int g    = lane >> 4;
    const int wc   = wid & 3;           // c_out tile (16 c)
    const int wp   = wid >> 2;          // px tile (16 px)

    const int bid  = blockIdx.x;        // 1024 = 8 b x 64 hs x 2 half
    const int half = bid & 1;
    const int hs   = (bid >> 1) & 63;
    const int b    = bid >> 7;
    const int c0   = cg * 4;

    // ---- prologue: S0, weights (16 coalesced loads -> 64 VGPR), S1 ----
    stage_tile(x, xbuf[0], 0, b, hs, half, wid, lane);    // S0 (4 ops/wave)
    __builtin_amdgcn_sched_barrier(0);
    short8v wrh[8], wrl[8];
    {
        const short8v* ph = (const short8v*)wh + (size_t)(wc * 8) * 64 + lane;
        const short8v* pl = (const short8v*)wl + (size_t)(wc * 8) * 64 + lane;
        #pragma unroll
        for (int ks = 0; ks < 8; ++ks) { wrh[ks] = ph[ks * 64]; wrl[ks] = pl[ks * 64]; }
    }
    __builtin_amdgcn_sched_barrier(0);
    stage_tile(x, xbuf[1], 1, b, hs, half, wid, lane);    // S1

    float mem[4] = {0.f, 0.f, 0.f, 0.f}, spk[4] = {0.f, 0.f, 0.f, 0.f};

    const int spw  = pxl * 256 + ((cg * 16) ^ ((pxl & 15) << 4));  // spike write
    const int bpx  = wp * 16 + l15;                                 // MFMA B pixel
    const int cb   = wc * 4 + g;                                    // c_out quad
    const int ywb  = bpx * 128 + ((cb * 8) ^ ((bpx & 7) << 3));     // y_lds write
    const int crow = tid >> 3;          // writeout c row
    const int pq   = tid & 7;           // writeout px quad

    #pragma unroll
    for (int t = 0; t < 4; ++t) {
        // ---- bar A: wait this t's stage group (counted; y-stores included) ----
        // vmem program order: S0(4) W(16) S1(4) | S2(4) yst0(1) | S3(4) yst1(1) | yst2(1)
        if (t == 0)      WAITV(20);   // retire S0
        else if (t == 1) WAITV(5);    // retire ..S1  (newer: S2x4 + yst0)
        else if (t == 2) WAITV(6);    // retire ..S2  (newer: yst0, S3x4, yst1)
        else             WAITV(2);    // retire ..S3  (newer: yst1, yst2)
        BAR();
        __builtin_amdgcn_sched_barrier(0);

        // ---- LIF t from LDS, p order = r0.x r0.y r1.x r1.y ----
        const uint8_t* xb = xbuf[t & 1];
        uint32_t pk[4];
        #pragma unroll
        for (int ci = 0; ci < 4; ++ci) {
            int qoff = ((c0 + ci) * 2) * 256 + pxl * 8;
            float2 r0v = *(const float2*)(xb + qoff);
            float2 r1v = *(const float2*)(xb + qoff + 256);
            float m = mem[ci], s = spk[ci], sv;
            uint32_t p;
            m = (m - s) * DECAYF + r0v.x;
            sv = rintf(fminf(fmaxf(m, 0.f), 4.f)); s = sv * 0.25f; p = (uint32_t)(int)sv;
            m = (m - s) * DECAYF + r0v.y;
            sv = rintf(fminf(fmaxf(m, 0.f), 4.f)); s = sv * 0.25f; p |= ((uint32_t)(int)sv) << 8;
            m = (m - s) * DECAYF + r1v.x;
            sv = rintf(fminf(fmaxf(m, 0.f), 4.f)); s = sv * 0.25f; p |= ((uint32_t)(int)sv) << 16;
            m = (m - s) * DECAYF + r1v.y;
            sv = rintf(fminf(fmaxf(m, 0.f), 4.f)); s = sv * 0.25f; p |= ((uint32_t)(int)sv) << 24;
            mem[ci] = m; spk[ci] = s; pk[ci] = p;
        }
        *(uint4*)(sp_lds + spw) = make_uint4(pk[0], pk[1], pk[2], pk[3]);
        WAITL0();
        BAR();      // bar B: spikes visible; xbuf[t&1] fully consumed

        // ---- prefetch t+2 into the buffer just freed ----
        if (t < 2) stage_tile(x, xbuf[t & 1], t + 2, b, hs, half, wid, lane);

        // ---- MFMA: 16 x 16x16x32 bf16, zero VMEM in this phase ----
        f32x4 acc = {0.f, 0.f, 0.f, 0.f};
        #pragma unroll
        for (int ks = 0; ks < 8; ++ks) {
            int k0 = ks * 32 + g * 8;
            int rb = bpx * 256 + (k0 ^ ((bpx & 15) << 4));
            uint2 sv2 = *(const uint2*)(sp_lds + rb);
            short8v bfv = unpack8(sv2.x, sv2.y);
            acc = __builtin_amdgcn_mfma_f32_16x16x32_bf16(wrh[ks], bfv, acc, 0, 0, 0);
            acc = __builtin_amdgcn_mfma_f32_16x16x32_bf16(wrl[ks], bfv, acc, 0, 0, 0);
        }

        // ---- epilogue: acc -> y_lds (C/D: col=l15=px, row=g*4+r=c) ----
        uint32_t lo = (uint32_t)f2bf_rn(acc[0]) | ((uint32_t)f2bf_rn(acc[1]) << 16);
        uint32_t hi = (uint32_t)f2bf_rn(acc[2]) | ((uint32_t)f2bf_rn(acc[3]) << 16);
        *(uint2*)(y_lds + ywb) = make_uint2(lo, hi);
        WAITL0();
        BAR();      // bar C: y_lds visible

        ushort v[4];
        #pragma unroll
        for (int j = 0; j < 4; ++j) {
            int pxj = pq * 4 + j;
            int addr = pxj * 128 + (((crow >> 2) * 8) ^ ((pxj & 7) << 3)) + (crow & 3) * 2;
            v[j] = *(const ushort*)(y_lds + addr);
        }
        uint2 o = make_uint2((uint32_t)v[0] | ((uint32_t)v[1] << 16),
                             (uint32_t)v[2] | ((uint32_t)v[3] << 16));
        ushort* yg = y + ((size_t)(t * Bn + b) * Cn + crow) * PX + hs * 64 + half * 32 + pq * 4;
        *(uint2*)yg = o;
        // next iteration's bar A orders y_lds/sp_lds reuse
    }
}

// ---------------------------------------------------------------------------
// Kernel 3 (rewritten): bilinear 2x upsample, vectorized.
// Thread = 8 output cols x one output-ROW-PAIR (2m, 2m+1) of one (tb,c).
// 16 lanes cover a full row pair. Loads: 3 coalesced uint2 (y rows m-1,m,m+1).
// Vertical blend first (linear, commutes), column halo via 2 shfl per blended
// row, then horizontal interp. Writes 4x float4.
// ---------------------------------------------------------------------------
__global__ __launch_bounds__(256) void upsample_kernel(const ushort* __restrict__ y,
                                                       float* __restrict__ out) {
    const int tid  = threadIdx.x;
    const int l    = tid & 15;
    const int lane = tid & 63;
    const int pr   = (blockIdx.x * 256 + tid) >> 4;   // 131072 row-pairs
    const int m    = pr & 63;
    const int c    = (pr >> 6) & 63;
    const int tb   = pr >> 12;

    const ushort* yp = y + ((size_t)tb * Cn + c) * PX;
    const int rm1 = (m == 0) ? 0 : m - 1;
    const int rp1 = (m == 63) ? 63 : m + 1;

    uint2 ua = *(const uint2*)(yp + rm1 * WsC + 4 * l);
    uint2 ub = *(const uint2*)(yp + m   * WsC + 4 * l);
    uint2 uc = *(const uint2*)(yp + rp1 * WsC + 4 * l);

    float a[4], b[4], cv[4];
    a[0] = bf2f((ushort)(ua.x & 0xffff)); a[1] = bf2f((ushort)(ua.x >> 16));
    a[2] = bf2f((ushort)(ua.y & 0xffff)); a[3] = bf2f((ushort)(ua.y >> 16));
    b[0] = bf2f((ushort)(ub.x & 0xffff)); b[1] = bf2f((ushort)(ub.x >> 16));
    b[2] = bf2f((ushort)(ub.y & 0xffff)); b[3] = bf2f((ushort)(ub.y >> 16));
    cv[0] = bf2f((ushort)(uc.x & 0xffff)); cv[1] = bf2f((ushort)(uc.x >> 16));
    cv[2] = bf2f((ushort)(uc.y & 0xffff)); cv[3] = bf2f((ushort)(uc.y >> 16));

    // vertical blend: e = source row for output 2m, o = for output 2m+1
    float e[4], o[4];
    #pragma unroll
    for (int j = 0; j < 4; ++j) {
        e[j] = 0.25f * a[j] + 0.75f * b[j];
        o[j] = 0.75f * b[j] + 0.25f * cv[j];
    }

    // column halo via shfl (groups of 16 are lane-contiguous; edges clamped)
    float e_prev = __shfl(e[3], lane - 1, 64); if (l == 0)  e_prev = e[0];
    float e_next = __shfl(e[0], lane + 1, 64); if (l == 15) e_next = e[3];
    float o_prev = __shfl(o[3], lane - 1, 64); if (l == 0)  o_prev = o[0];
    float o_next = __shfl(o[0], lane + 1, 64); if (l == 15) o_next = o[3];

    // horizontal: out[2k] = 0.25*in[k-1]+0.75*in[k]; out[2k+1]=0.75*in[k]+0.25*in[k+1]
    float4 r0a, r0b, r1a, r1b;
    r0a.x = 0.25f * e_prev + 0.75f * e[0];
    r0a.y = 0.75f * e[0]   + 0.25f * e[1];
    r0a.z = 0.25f * e[0]   + 0.75f * e[1];
    r0a.w = 0.75f * e[1]   + 0.25f * e[2];
    r0b.x = 0.25f * e[1]   + 0.75f * e[2];
    r0b.y = 0.75f * e[2]   + 0.25f * e[3];
    r0b.z = 0.25f * e[2]   + 0.75f * e[3];
    r0b.w = 0.75f * e[3]   + 0.25f * e_next;
    r1a.x = 0.25f * o_prev + 0.75f * o[0];
    r1a.y = 0.75f * o[0]   + 0.25f * o[1];
    r1a.z = 0.25f * o[0]   + 0.75f * o[1];
    r1a.w = 0.75f * o[1]   + 0.25f * o[2];
    r1b.x = 0.25f * o[1]   + 0.75f * o[2];
    r1b.y = 0.75f * o[2]   + 0.25f * o[3];
    r1b.z = 0.25f * o[2]   + 0.75f * o[3];
    r1b.w = 0.75f * o[3]   + 0.25f * o_next;

    float* op = out + ((size_t)tb * Cn + c) * (Hn * Wn) + (size_t)(2 * m) * Wn + 8 * l;
    *(float4*)(op)          = r0a;
    *(float4*)(op + 4)      = r0b;
    *(float4*)(op + Wn)     = r1a;
    *(float4*)(op + Wn + 4) = r1b;
}

// ---------------------------------------------------------------------------
extern "C" void kernel_launch(void* const* d_in, const int* in_sizes, int n_in,
                              void* d_out, int out_size, void* d_ws, size_t ws_size,
                              hipStream_t stream) {
    const float* x = (const float*)d_in[0];
    const float* w = (const float*)d_in[1];
    float* out = (float*)d_out;

    ushort* y   = (ushort*)d_ws;                                  // 16,777,216 B
    ushort* whi = (ushort*)((uint8_t*)d_ws + (size_t)16777216);   // 32,768 B
    ushort* wlo = (ushort*)((uint8_t*)d_ws + (size_t)16809984);   // 32,768 B

    wprep_kernel<<<8, 256, 0, stream>>>(w, whi, wlo);
    fused_lif_conv<<<1024, 512, 0, stream>>>(x, whi, wlo, y);
    upsample_kernel<<<8192, 256, 0, stream>>>(y, out);
}

// Round 9
// 58.939 us; speedup vs baseline: 1.1279x; 1.1279x over previous
//
#include <hip/hip_runtime.h>
#include <stdint.h>

constexpr int Bn = 8, Cn = 64, Hn = 128, Wn = 128;
constexpr int HsC = 64, WsC = 64;
constexpr int Kn = 256;                 // C * r^2
constexpr int PX = HsC * WsC;           // 4096 pixels per (t,b) plane
constexpr float DECAYF = 0.25f;

typedef __attribute__((ext_vector_type(8))) short short8v;
typedef __attribute__((ext_vector_type(4))) float f32x4;

#define WAITV(N) asm volatile("s_waitcnt vmcnt(" #N ")" ::: "memory")
#define WAITL0() asm volatile("s_waitcnt lgkmcnt(0)" ::: "memory")
#define BAR() __builtin_amdgcn_s_barrier()

static __device__ __forceinline__ ushort f2bf_rn(float f) {
    uint32_t u = __float_as_uint(f);
    uint32_t r = (u + 0x7FFFu + ((u >> 16) & 1u)) >> 16;
    return (ushort)r;
}
static __device__ __forceinline__ float bf2f(ushort u) {
    return __uint_as_float(((uint32_t)u) << 16);
}

// u8 spikes (0..4) -> 8 bf16 via v_perm byte-LUT (exact). Verified.
static __device__ __forceinline__ short8v unpack8(uint32_t s0, uint32_t s1) {
    uint32_t lo0 = __builtin_amdgcn_perm(0x00000080u, 0x40008000u, s0);
    uint32_t hi0 = __builtin_amdgcn_perm(0x00000040u, 0x40403F00u, s0);
    uint32_t lo1 = __builtin_amdgcn_perm(0x00000080u, 0x40008000u, s1);
    uint32_t hi1 = __builtin_amdgcn_perm(0x00000040u, 0x40403F00u, s1);
    union { uint32_t u[4]; short8v s; } r;
    r.u[0] = __builtin_amdgcn_perm(hi0, lo0, 0x05010400u);
    r.u[1] = __builtin_amdgcn_perm(hi0, lo0, 0x07030602u);
    r.u[2] = __builtin_amdgcn_perm(hi1, lo1, 0x05010400u);
    r.u[3] = __builtin_amdgcn_perm(hi1, lo1, 0x07030602u);
    return r.s;
}

// async 16B global -> LDS (no dest VGPRs; queue depth = vmcnt)
static __device__ __forceinline__ void gload_lds16(const void* gsrc, void* ldst) {
    __builtin_amdgcn_global_load_lds((const __attribute__((address_space(1))) uint32_t*)gsrc,
                                     (__attribute__((address_space(3))) uint32_t*)ldst, 16, 0, 0);
}

// ---------------------------------------------------------------------------
// Kernel 0: weight prep — fold /4, split bf16 hi+lo, PERMUTED for the conv's
// register preload: dst[((wc*8+ks)*64 + lane)*8 + j] =
//   wq(row = wc*16 + (lane&15), k = ks*32 + (lane>>4)*8 + j)
// ---------------------------------------------------------------------------
__global__ __launch_bounds__(256) void wprep_kernel(const float* __restrict__ w,
                                                    ushort* __restrict__ wh,
                                                    ushort* __restrict__ wl) {
    int gid = blockIdx.x * 256 + threadIdx.x;   // 2048 total
    int lane = gid & 63, ks = (gid >> 6) & 7, wc = gid >> 9;
    int row = wc * 16 + (lane & 15);
    int kb = ks * 32 + (lane >> 4) * 8;
    #pragma unroll
    for (int j = 0; j < 8; ++j) {
        float wq = w[row * 256 + kb + j] * 0.25f;
        ushort h = f2bf_rn(wq);
        wh[gid * 8 + j] = h;
        wl[gid * 8 + j] = f2bf_rn(wq - bf2f(h));
    }
}

// ---------------------------------------------------------------------------
// stage one t's x tile (64c x 2rows x 32cols = 16KB) into LDS buffer.
// chunk q = c*2+row (128B); per wave 4 x 1KB gload_lds (8 chunks each).
// ---------------------------------------------------------------------------
static __device__ __forceinline__ void stage_tile(const float* __restrict__ x,
                                                  uint8_t* xb, int t, int b,
                                                  int hs, int quarter, int wid, int lane) {
    const size_t tstr = (size_t)Bn * Cn * Hn * Wn;
    #pragma unroll
    for (int i = 0; i < 4; ++i) {
        int grp = i * 4 + wid;              // 0..15, 1KB each
        int q = 8 * grp + (lane >> 3);      // chunk 0..127
        int cch = q >> 1, row = q & 1;
        const float* gsrc = x + (size_t)t * tstr + ((size_t)b * Cn + cch) * (Hn * Wn)
                            + (2 * hs + row) * Wn + quarter * 32 + (lane & 7) * 4;
        gload_lds16(gsrc, xb + (size_t)grp * 1024);
    }
}

// ---------------------------------------------------------------------------
// Fused LIF + 1x1 conv (low res; conv commutes with bilinear upsample).
// Round-8: 256 threads / 16 px per block, LDS 38KB -> 4 blocks/CU (was 2).
// vmcnt ledger IDENTICAL to the verified round-6 structure:
// prologue S0(4) W(16) S1(4); per t: stage(4) + ystore(1).
// ---------------------------------------------------------------------------
__global__ __launch_bounds__(256, 4) void fused_lif_conv(const float* __restrict__ x,
                                                         const ushort* __restrict__ wh,
                                                         const ushort* __restrict__ wl,
                                                         ushort* __restrict__ y) {
    __shared__ __align__(16) uint8_t xbuf[2][16 * 1024];  // 32 KB double-buffer
    __shared__ __align__(16) uint8_t sp_lds[16 * 256];    // 4 KB spikes [px][k]
    __shared__ __align__(8)  uint8_t y_lds[16 * 128];     // 2 KB [px][c] bf16

    const int tid  = threadIdx.x;
    const int pxl  = tid & 15;          // local pixel (LIF role)
    const int cg   = tid >> 4;          // 0..15 -> channels cg*4..cg*4+3
    const int lane = tid & 63;
    const int wid  = tid >> 6;          // 0..3
    const int l15  = lane & 15;
    const int g    = lane >> 4;
    const int wc   = wid;               // c_out tile (16 c)

    const int bid     = blockIdx.x;     // 2048 = 8 b x 64 hs x 4 quarter
    const int quarter = bid & 3;
    const int hs      = (bid >> 2) & 63;
    const int b       = bid >> 8;
    const int c0      = cg * 4;

    // ---- prologue: S0, weights (16 coalesced loads -> 64 VGPR), S1 ----
    stage_tile(x, xbuf[0], 0, b, hs, quarter, wid, lane);    // S0 (4 ops/wave)
    __builtin_amdgcn_sched_barrier(0);
    short8v wrh[8], wrl[8];
    {
        const short8v* ph = (const short8v*)wh + (size_t)(wc * 8) * 64 + lane;
        const short8v* pl = (const short8v*)wl + (size_t)(wc * 8) * 64 + lane;
        #pragma unroll
        for (int ks = 0; ks < 8; ++ks) { wrh[ks] = ph[ks * 64]; wrl[ks] = pl[ks * 64]; }
    }
    __builtin_amdgcn_sched_barrier(0);
    stage_tile(x, xbuf[1], 1, b, hs, quarter, wid, lane);    // S1

    float mem[4] = {0.f, 0.f, 0.f, 0.f}, spk[4] = {0.f, 0.f, 0.f, 0.f};

    const int spw  = pxl * 256 + ((cg * 16) ^ ((pxl & 15) << 4));  // spike write
    const int bpx  = l15;                                           // MFMA B pixel
    const int cb   = wc * 4 + g;                                    // c_out quad
    const int ywb  = bpx * 128 + ((cb * 8) ^ ((bpx & 7) << 3));     // y_lds write
    const int crow = tid >> 2;          // writeout c row 0..63
    const int pq   = tid & 3;           // writeout px quad 0..3

    #pragma unroll
    for (int t = 0; t < 4; ++t) {
        // ---- bar A: wait this t's stage group (counted; y-stores included) ----
        // vmem order: S0(4) W(16) S1(4) | S2(4) yst0 | S3(4) yst1 | yst2
        if (t == 0)      WAITV(20);   // retire S0
        else if (t == 1) WAITV(5);    // retire ..S1
        else if (t == 2) WAITV(6);    // retire ..S2
        else             WAITV(2);    // retire ..S3
        BAR();
        __builtin_amdgcn_sched_barrier(0);

        // ---- LIF t from LDS, p order = r0.x r0.y r1.x r1.y ----
        const uint8_t* xb = xbuf[t & 1];
        uint32_t pk[4];
        #pragma unroll
        for (int ci = 0; ci < 4; ++ci) {
            int qoff = (c0 + ci) * 256 + pxl * 8;
            float2 r0v = *(const float2*)(xb + qoff);
            float2 r1v = *(const float2*)(xb + qoff + 128);
            float m = mem[ci], s = spk[ci], sv;
            uint32_t p;
            m = (m - s) * DECAYF + r0v.x;
            sv = rintf(fminf(fmaxf(m, 0.f), 4.f)); s = sv * 0.25f; p = (uint32_t)(int)sv;
            m = (m - s) * DECAYF + r0v.y;
            sv = rintf(fminf(fmaxf(m, 0.f), 4.f)); s = sv * 0.25f; p |= ((uint32_t)(int)sv) << 8;
            m = (m - s) * DECAYF + r1v.x;
            sv = rintf(fminf(fmaxf(m, 0.f), 4.f)); s = sv * 0.25f; p |= ((uint32_t)(int)sv) << 16;
            m = (m - s) * DECAYF + r1v.y;
            sv = rintf(fminf(fmaxf(m, 0.f), 4.f)); s = sv * 0.25f; p |= ((uint32_t)(int)sv) << 24;
            mem[ci] = m; spk[ci] = s; pk[ci] = p;
        }
        *(uint4*)(sp_lds + spw) = make_uint4(pk[0], pk[1], pk[2], pk[3]);
        WAITL0();
        BAR();      // bar B: spikes visible; xbuf[t&1] fully consumed

        // ---- prefetch t+2 into the buffer just freed ----
        if (t < 2) stage_tile(x, xbuf[t & 1], t + 2, b, hs, quarter, wid, lane);

        // ---- MFMA: 16 x 16x16x32 bf16, zero VMEM in this phase ----
        f32x4 acc = {0.f, 0.f, 0.f, 0.f};
        #pragma unroll
        for (int ks = 0; ks < 8; ++ks) {
            int k0 = ks * 32 + g * 8;
            int rb = bpx * 256 + (k0 ^ ((bpx & 15) << 4));
            uint2 sv2 = *(const uint2*)(sp_lds + rb);
            short8v bfv = unpack8(sv2.x, sv2.y);
            acc = __builtin_amdgcn_mfma_f32_16x16x32_bf16(wrh[ks], bfv, acc, 0, 0, 0);
            acc = __builtin_amdgcn_mfma_f32_16x16x32_bf16(wrl[ks], bfv, acc, 0, 0, 0);
        }

        // ---- epilogue: acc -> y_lds (C/D: col=l15=px, row=g*4+r=c) ----
        uint32_t lo = (uint32_t)f2bf_rn(acc[0]) | ((uint32_t)f2bf_rn(acc[1]) << 16);
        uint32_t hi = (uint32_t)f2bf_rn(acc[2]) | ((uint32_t)f2bf_rn(acc[3]) << 16);
        *(uint2*)(y_lds + ywb) = make_uint2(lo, hi);
        WAITL0();
        BAR();      // bar C: y_lds visible

        ushort v[4];
        #pragma unroll
        for (int j = 0; j < 4; ++j) {
            int pxj = pq * 4 + j;
            int addr = pxj * 128 + (((crow >> 2) * 8) ^ ((pxj & 7) << 3)) + (crow & 3) * 2;
            v[j] = *(const ushort*)(y_lds + addr);
        }
        uint2 o = make_uint2((uint32_t)v[0] | ((uint32_t)v[1] << 16),
                             (uint32_t)v[2] | ((uint32_t)v[3] << 16));
        ushort* yg = y + ((size_t)(t * Bn + b) * Cn + crow) * PX
                       + hs * 64 + quarter * 16 + pq * 4;
        *(uint2*)yg = o;
        // next iteration's bar A orders y_lds/sp_lds reuse
    }
}

// ---------------------------------------------------------------------------
// Kernel 3: bilinear 2x upsample with CONTIGUOUS stores.
// Thread = 4 consecutive output cols (4sl..4sl+3) of ONE output row; a
// 32-lane group writes a full 512B row per instruction. Per thread: 2 aligned
// uint loads (src cols 2sl,2sl+1 of the 2 vertical source rows), vertical
// blend, column halo via 2 shfl (clamped at sl=0/31), 1 NT f32x4 store.
// ---------------------------------------------------------------------------
__global__ __launch_bounds__(256) void upsample_kernel(const ushort* __restrict__ y,
                                                       float* __restrict__ out) {
    const int gg   = blockIdx.x * 256 + threadIdx.x;  // 8388608 threads
    const int sl   = gg & 31;                          // col quad within row
    const int row  = gg >> 5;                          // global output row
    const int h    = row & 127;
    const int c    = (row >> 7) & 63;
    const int tb   = row >> 13;
    const int lane = threadIdx.x & 63;

    const ushort* yp = y + ((size_t)tb * Cn + c) * PX;
    const int m   = h >> 1;
    const int odd = h & 1;
    const int rA = odd ? m : ((m == 0) ? 0 : m - 1);
    const int rB = odd ? ((m == 63) ? 63 : m + 1) : m;
    const float wA = odd ? 0.75f : 0.25f;
    const float wB = odd ? 0.25f : 0.75f;

    uint32_t ua = *(const uint32_t*)(yp + rA * WsC + 2 * sl);
    uint32_t ub = *(const uint32_t*)(yp + rB * WsC + 2 * sl);

    float e0 = wA * bf2f((ushort)(ua & 0xffff)) + wB * bf2f((ushort)(ub & 0xffff));
    float e1 = wA * bf2f((ushort)(ua >> 16))    + wB * bf2f((ushort)(ub >> 16));

    float eprev = __shfl(e1, lane - 1, 64); if (sl == 0)  eprev = e0;
    float enext = __shfl(e0, lane + 1, 64); if (sl == 31) enext = e1;

    f32x4 o;
    o.x = 0.25f * eprev + 0.75f * e0;
    o.y = 0.75f * e0    + 0.25f * e1;
    o.z = 0.25f * e0    + 0.75f * e1;
    o.w = 0.75f * e1    + 0.25f * enext;

    f32x4* dst = (f32x4*)(out + ((size_t)tb * Cn + c) * (Hn * Wn)
                              + (size_t)h * Wn + 4 * sl);
    __builtin_nontemporal_store(o, dst);
}

// ---------------------------------------------------------------------------
extern "C" void kernel_launch(void* const* d_in, const int* in_sizes, int n_in,
                              void* d_out, int out_size, void* d_ws, size_t ws_size,
                              hipStream_t stream) {
    const float* x = (const float*)d_in[0];
    const float* w = (const float*)d_in[1];
    float* out = (float*)d_out;

    ushort* y   = (ushort*)d_ws;                                  // 16,777,216 B
    ushort* whi = (ushort*)((uint8_t*)d_ws + (size_t)16777216);   // 32,768 B
    ushort* wlo = (ushort*)((uint8_t*)d_ws + (size_t)16809984);   // 32,768 B

    wprep_kernel<<<8, 256, 0, stream>>>(w, whi, wlo);
    fused_lif_conv<<<2048, 256, 0, stream>>>(x, whi, wlo, y);
    upsample_kernel<<<32768, 256, 0, stream>>>(y, out);
}